// Round 1
// baseline (263.512 us; speedup 1.0000x reference)
//
#include <hip/hip_runtime.h>

constexpr int L = 128;

__global__ __launch_bounds__(256) void xfel_proj(
    const float* __restrict__ rotmat,   // [B,3,3]
    const float* __restrict__ vol,      // [L,L,L] as [D,H,W]
    float* __restrict__ out)            // [B,L,L]
{
    const int tid = threadIdx.x;
    const int j = (blockIdx.x << 1) | (tid >> 7);   // image row
    const int k = tid & (L - 1);                     // image col
    const int b = blockIdx.y;
    const int oidx = (b * L + j) * L + k;

    // --- circular mask (computed inline; margin to threshold >> fp32 eps) ---
    const float step = 128.0f / 127.0f;
    const float aj = (float)(j - 64) * step;
    const float ak = (float)(k - 64) * step;
    const float thr = 57.6f * 57.6f;                 // (L/2 * 0.9)^2
    if (aj * aj + ak * ak >= thr) {
        __builtin_nontemporal_store(0.0f, out + oidx);
        return;
    }

    // --- rotate plane point (row-vector p @ R) ---
    const float* __restrict__ R = rotmat + b * 9;    // uniform per block -> s_load
    const float lj = -1.0f + (float)j * (2.0f / 127.0f);
    const float lk = -1.0f + (float)k * (2.0f / 127.0f);
    const float yc = -1.0f + 64.0f * (2.0f / 127.0f); // lin[64]

    const float px = lj * R[0] + yc * R[3] + lk * R[6];
    const float py = lj * R[1] + yc * R[4] + lk * R[7];
    const float pz = lj * R[2] + yc * R[5] + lk * R[8];

    // --- grid_sample: align_corners=True mapping to voxel coords ---
    const float gx = (px + 1.0f) * 63.5f;
    const float gy = (py + 1.0f) * 63.5f;
    const float gz = (pz + 1.0f) * 63.5f;

    const float fx0 = floorf(gx), fy0 = floorf(gy), fz0 = floorf(gz);
    const float fx = gx - fx0, fy = gy - fy0, fz = gz - fz0;
    const int ix = (int)fx0, iy = (int)fy0, iz = (int)fz0;

    // whole stencil outside -> 0 (zeros padding)
    if (ix < -1 || ix >= L || iy < -1 || iy >= L || iz < -1 || iz >= L) {
        __builtin_nontemporal_store(0.0f, out + oidx);
        return;
    }

    // per-corner validity folded into weights (== where(valid, v, 0))
    const float wx0 = (ix >= 0)     ? (1.0f - fx) : 0.0f;
    const float wx1 = (ix + 1 < L)  ? fx          : 0.0f;
    const float wy0 = (iy >= 0)     ? (1.0f - fy) : 0.0f;
    const float wy1 = (iy + 1 < L)  ? fy          : 0.0f;
    const float wz0 = (iz >= 0)     ? (1.0f - fz) : 0.0f;
    const float wz1 = (iz + 1 < L)  ? fz          : 0.0f;

    const int x0 = max(ix, 0), x1 = min(ix + 1, L - 1);
    const int y0 = max(iy, 0), y1 = min(iy + 1, L - 1);
    const int z0 = max(iz, 0), z1 = min(iz + 1, L - 1);

    const float* __restrict__ p0 = vol + z0 * L * L;
    const float* __restrict__ p1 = vol + z1 * L * L;
    const float v000 = p0[y0 * L + x0];
    const float v001 = p0[y0 * L + x1];
    const float v010 = p0[y1 * L + x0];
    const float v011 = p0[y1 * L + x1];
    const float v100 = p1[y0 * L + x0];
    const float v101 = p1[y0 * L + x1];
    const float v110 = p1[y1 * L + x0];
    const float v111 = p1[y1 * L + x1];

    const float r0 = wy0 * (wx0 * v000 + wx1 * v001) + wy1 * (wx0 * v010 + wx1 * v011);
    const float r1 = wy0 * (wx0 * v100 + wx1 * v101) + wy1 * (wx0 * v110 + wx1 * v111);
    const float res = wz0 * r0 + wz1 * r1;

    __builtin_nontemporal_store(res, out + oidx);
}

extern "C" void kernel_launch(void* const* d_in, const int* in_sizes, int n_in,
                              void* d_out, int out_size, void* d_ws, size_t ws_size,
                              hipStream_t stream) {
    const float* rotmat = (const float*)d_in[0];
    const float* vol    = (const float*)d_in[1];
    float* out          = (float*)d_out;
    const int B = in_sizes[0] / 9;           // 2048
    dim3 grid(L / 2, B);                     // 2 rows of j per 256-thread block
    xfel_proj<<<grid, dim3(256), 0, stream>>>(rotmat, vol, out);
}